// Round 10
// baseline (40004.678 us; speedup 1.0000x reference)
//
#include <hip/hip_runtime.h>
#include <hip/hip_fp16.h>
#include <math.h>

#define T_LEN 2048
#define NB 8
#define DD 512
#define HH 512
#define G4 2048   // 4*H
#define CAT2H 1024

// ---------- vector load/store helpers (fp32 or fp16 <-> float4) ----------
__device__ __forceinline__ float4 ld4(const float* p) { return *(const float4*)p; }
__device__ __forceinline__ float4 ld4(const __half* p) {
  const __half2 a = *(const __half2*)p;
  const __half2 b = *(const __half2*)(p + 2);
  return make_float4(__half2float(a.x), __half2float(a.y),
                     __half2float(b.x), __half2float(b.y));
}
__device__ __forceinline__ void st4(float* p, float4 v) { *(float4*)p = v; }
__device__ __forceinline__ void st4(__half* p, float4 v) {
  *(__half2*)p = __floats2half2_rn(v.x, v.y);
  *(__half2*)(p + 2) = __floats2half2_rn(v.z, v.w);
}

// ---------------- tiled GEMM with bias: C = A(MxK) @ B(KxN) + bias ----------------
template <typename TA, typename TC>
__global__ __launch_bounds__(256) void gemm_bias(
    const TA* __restrict__ A, const float* __restrict__ B,
    const float* __restrict__ bias, TC* __restrict__ C,
    int M, int N, int K) {
  __shared__ float As[16][128];
  __shared__ float Bs[16][128];
  const int nTiles = N >> 7;
  const int bx = blockIdx.x % nTiles;
  const int by = blockIdx.x / nTiles;
  const int tid = threadIdx.x;
  const int tx = tid & 15, ty = tid >> 4;
  const TA* Ab = A + (size_t)by * 128 * K;
  const float* Bb = B + ((size_t)bx << 7);
  float acc[8][8];
#pragma unroll
  for (int i = 0; i < 8; i++)
#pragma unroll
    for (int j = 0; j < 8; j++) acc[i][j] = 0.f;

  for (int k0 = 0; k0 < K; k0 += 16) {
    __syncthreads();
#pragma unroll
    for (int i = 0; i < 2; i++) {
      int idx = i * 256 + tid;
      int m = idx >> 2, kv = idx & 3;
      float4 va = ld4(Ab + (size_t)m * K + k0 + kv * 4);
      As[kv * 4 + 0][m] = va.x;
      As[kv * 4 + 1][m] = va.y;
      As[kv * 4 + 2][m] = va.z;
      As[kv * 4 + 3][m] = va.w;
      int kk = idx >> 5, nv = idx & 31;
      float4 vb = ld4(Bb + (size_t)(k0 + kk) * N + nv * 4);
      *(float4*)&Bs[kk][nv * 4] = vb;
    }
    __syncthreads();
#pragma unroll
    for (int kk = 0; kk < 16; kk++) {
      float a[8], bb[8];
      *(float4*)&a[0] = *(const float4*)&As[kk][ty * 8];
      *(float4*)&a[4] = *(const float4*)&As[kk][ty * 8 + 4];
      *(float4*)&bb[0] = *(const float4*)&Bs[kk][tx * 8];
      *(float4*)&bb[4] = *(const float4*)&Bs[kk][tx * 8 + 4];
#pragma unroll
      for (int i = 0; i < 8; i++)
#pragma unroll
        for (int j = 0; j < 8; j++) acc[i][j] = fmaf(a[i], bb[j], acc[i][j]);
    }
  }
  const int row0 = by * 128 + ty * 8;
  const int col0 = bx * 128 + tx * 8;
  float bv[8];
  *(float4*)&bv[0] = *(const float4*)&bias[col0];
  *(float4*)&bv[4] = *(const float4*)&bias[col0 + 4];
#pragma unroll
  for (int i = 0; i < 8; i++) {
    float4 o0 = make_float4(acc[i][0] + bv[0], acc[i][1] + bv[1],
                            acc[i][2] + bv[2], acc[i][3] + bv[3]);
    float4 o1 = make_float4(acc[i][4] + bv[4], acc[i][5] + bv[5],
                            acc[i][6] + bv[6], acc[i][7] + bv[7]);
    st4(&C[(size_t)(row0 + i) * N + col0], o0);
    st4(&C[(size_t)(row0 + i) * N + col0 + 4], o1);
  }
}

// ---------------- persistent bidirectional LSTM scan, depth-2 interleaved ----------
// 128 WGs x 512 threads. Group of 16 WGs = pair q: two SAME-DIRECTION batches
// (b0=2j, b1=2j+1) sharing Wh (same wr[128] registers). Macro-step: slot A
// (chain ci0) then slot B (chain ci1); both mailbox polls issued at macro
// start, so each chain's publish gets ~a slot of flight time before its next
// consumption -> the LLC visibility+discovery latency is hidden by the other
// chain's compute. Protocol = R5's proven scheme verbatim: u64 (tag|f32 h)
// relaxed AGENT atomics, double-buffered by step parity, tags unique per
// launch (bases 1/3000), timeout -> diag marker (never silent corruption).
__device__ __forceinline__ float sigmf_(float x) {
  return 1.f / (1.f + __expf(-x));
}
__device__ __forceinline__ float tanhf_(float x) {
  return 1.f - 2.f / (1.f + __expf(2.f * x));
}
__device__ __forceinline__ unsigned long long agld_(const unsigned long long* p) {
  return __hip_atomic_load(p, __ATOMIC_RELAXED, __HIP_MEMORY_SCOPE_AGENT);
}

__global__ __launch_bounds__(512, 2) void lstm_scan(
    const __half* __restrict__ Pf, const __half* __restrict__ Pb,
    const float* __restrict__ Whf, const float* __restrict__ Whb,
    const int* __restrict__ seqlen, __half* __restrict__ cat,
    unsigned long long* hbuf, float* diag, int tagbase) {
  const int w = blockIdx.x;
  const int q = w & 7;     // pair id
  const int us = w >> 3;   // 0..15: 32-unit slice
  const int dir = q >> 2;  // 0..1
  const int b0 = (q & 3) * 2;
  const int b1 = b0 + 1;
  const int ci0 = dir * NB + b0;
  const int ci1 = ci0 + 1;
  const int t = threadIdx.x;
  const int col = t & 127;
  const int kc = t >> 7;
  const int C = (col >> 5) * HH + us * 32 + (col & 31);

  const float* __restrict__ Wh = dir ? Whb : Whf;
  const __half* __restrict__ P = dir ? Pb : Pf;
  const int L0 = seqlen[b0];
  const int L1 = seqlen[b1];

  __shared__ float h_lds[HH];
  __shared__ float partial[4][128];

  float wr[128];
  {
    const float* wp = Wh + (size_t)(kc * 128) * G4 + C;
#pragma unroll
    for (int j = 0; j < 128; j++) wr[j] = wp[(size_t)j * G4];
  }
  float cs0 = 0.f, cs1 = 0.f;

  // hbuf: [slot(2)][ci(16)][unit(512)] u64 (tag<<32 | f32 h bits)
  const size_t slotD = (size_t)16 * HH;
  const unsigned tb = (unsigned)tagbase;

  // init slot 0: h(-1)=0 tagged tb for own units, both chains
  if (t < 32) {
    unsigned long long pv = ((unsigned long long)tb << 32);
    __hip_atomic_store(hbuf + (size_t)ci0 * HH + us * 32 + t, pv,
                       __ATOMIC_RELAXED, __HIP_MEMORY_SCOPE_AGENT);
    __hip_atomic_store(hbuf + (size_t)ci1 * HH + us * 32 + t, pv,
                       __ATOMIC_RELAXED, __HIP_MEMORY_SCOPE_AGENT);
  }

  for (int s = 0; s < T_LEN; s++) {
    const unsigned want = tb + (unsigned)s;
    const int tin0 = dir ? ((s < L0) ? (L0 - 1 - s) : s) : s;
    const int tin1 = dir ? ((s < L1) ? (L1 - 1 - s) : s) : s;

    // issue BOTH polls up front (B's flies during slot A)
    const unsigned long long* hp0 =
        hbuf + (size_t)(s & 1) * slotD + (size_t)ci0 * HH + t;
    const unsigned long long* hp1 =
        hbuf + (size_t)(s & 1) * slotD + (size_t)ci1 * HH + t;
    unsigned long long v0 = agld_(hp0);
    unsigned long long v1 = agld_(hp1);

    float p0 = 0.f, p1 = 0.f, p2 = 0.f, p3 = 0.f;
    float q0 = 0.f, q1 = 0.f, q2 = 0.f, q3 = 0.f;
    if (t < 32) {  // prefetch P rows for both batches; hides under spin A
      const __half* pr0 = P + ((size_t)b0 * T_LEN + tin0) * G4 + us * 32 + t;
      const __half* pr1 = P + ((size_t)b1 * T_LEN + tin1) * G4 + us * 32 + t;
      p0 = __half2float(pr0[0]);
      p1 = __half2float(pr0[HH]);
      p2 = __half2float(pr0[2 * HH]);
      p3 = __half2float(pr0[3 * HH]);
      q0 = __half2float(pr1[0]);
      q1 = __half2float(pr1[HH]);
      q2 = __half2float(pr1[2 * HH]);
      q3 = __half2float(pr1[3 * HH]);
    }

    // ---- slot A: chain ci0 ----
    int dead = 0;
    {
      int tries = 0;
      while ((unsigned)(v0 >> 32) != want) {
        v0 = agld_(hp0);
        if (++tries > (1 << 20)) { dead = 1; break; }
      }
      h_lds[t] = __uint_as_float((unsigned)v0);
    }
    if (__syncthreads_or(dead)) {  // barrier B_A
      if (t == 0) { atomicAdd(diag + 1, 1.0f); diag[2] = (float)s; }
      break;
    }
    {
      float a0 = 0.f, a1 = 0.f, a2 = 0.f, a3 = 0.f;
      const float* hk = &h_lds[kc * 128];
#pragma unroll
      for (int jj = 0; jj < 32; jj++) {
        float4 hv = *(const float4*)&hk[jj * 4];
        a0 = fmaf(hv.x, wr[jj * 4 + 0], a0);
        a1 = fmaf(hv.y, wr[jj * 4 + 1], a1);
        a2 = fmaf(hv.z, wr[jj * 4 + 2], a2);
        a3 = fmaf(hv.w, wr[jj * 4 + 3], a3);
      }
      partial[kc][col] = (a0 + a1) + (a2 + a3);
    }
    __syncthreads();  // barrier C_A
    if (t < 32) {     // finale A (overlaps other threads' slot-B spin)
      float g0 = p0, g1 = p1, g2 = p2, g3 = p3;
#pragma unroll
      for (int k2 = 0; k2 < 4; k2++) {
        g0 += partial[k2][t];
        g1 += partial[k2][32 + t];
        g2 += partial[k2][64 + t];
        g3 += partial[k2][96 + t];
      }
      cs0 = sigmf_(g1) * cs0 + sigmf_(g0) * tanhf_(g2);
      float hn = sigmf_(g3) * tanhf_(cs0);
      unsigned long long pv = ((unsigned long long)(want + 1u) << 32) |
                              (unsigned long long)__float_as_uint(hn);
      __hip_atomic_store(
          hbuf + (size_t)((s + 1) & 1) * slotD + (size_t)ci0 * HH + us * 32 + t,
          pv, __ATOMIC_RELAXED, __HIP_MEMORY_SCOPE_AGENT);
      cat[((size_t)b0 * T_LEN + tin0) * CAT2H + dir * HH + us * 32 + t] =
          __float2half(hn);
    }

    // ---- slot B: chain ci1 (h_lds safely reusable: all passed C_A) ----
    dead = 0;
    {
      int tries = 0;
      while ((unsigned)(v1 >> 32) != want) {
        v1 = agld_(hp1);
        if (++tries > (1 << 20)) { dead = 1; break; }
      }
      h_lds[t] = __uint_as_float((unsigned)v1);
    }
    if (__syncthreads_or(dead)) {  // barrier B_B (also fences finale A)
      if (t == 0) { atomicAdd(diag + 1, 1.0f); diag[2] = (float)s; }
      break;
    }
    {
      float a0 = 0.f, a1 = 0.f, a2 = 0.f, a3 = 0.f;
      const float* hk = &h_lds[kc * 128];
#pragma unroll
      for (int jj = 0; jj < 32; jj++) {
        float4 hv = *(const float4*)&hk[jj * 4];
        a0 = fmaf(hv.x, wr[jj * 4 + 0], a0);
        a1 = fmaf(hv.y, wr[jj * 4 + 1], a1);
        a2 = fmaf(hv.z, wr[jj * 4 + 2], a2);
        a3 = fmaf(hv.w, wr[jj * 4 + 3], a3);
      }
      partial[kc][col] = (a0 + a1) + (a2 + a3);
    }
    __syncthreads();  // barrier C_B
    if (t < 32) {     // finale B (overlaps next macro's slot-A spin)
      float g0 = q0, g1 = q1, g2 = q2, g3 = q3;
#pragma unroll
      for (int k2 = 0; k2 < 4; k2++) {
        g0 += partial[k2][t];
        g1 += partial[k2][32 + t];
        g2 += partial[k2][64 + t];
        g3 += partial[k2][96 + t];
      }
      cs1 = sigmf_(g1) * cs1 + sigmf_(g0) * tanhf_(g2);
      float hn = sigmf_(g3) * tanhf_(cs1);
      unsigned long long pv = ((unsigned long long)(want + 1u) << 32) |
                              (unsigned long long)__float_as_uint(hn);
      __hip_atomic_store(
          hbuf + (size_t)((s + 1) & 1) * slotD + (size_t)ci1 * HH + us * 32 + t,
          pv, __ATOMIC_RELAXED, __HIP_MEMORY_SCOPE_AGENT);
      cat[((size_t)b1 * T_LEN + tin1) * CAT2H + dir * HH + us * 32 + t] =
          __float2half(hn);
    }
    // no trailing barrier: next macro's h_lds writes gated by barrier B_A(s+1);
    // partial rewrite gated likewise. Same proof as R5.
  }
}

// Failure-signature marker: writes a decodable code into out[0] ONLY on failure.
__global__ void diag_mark(const float* diag, float* out, float code_ws, int wsfail) {
  if (wsfail) { out[0] = code_ws; return; }
  float nd = diag[1];
  if (nd > 0.f) out[0] = 1.0e7f + nd * 1.0e4f + diag[2];
}

extern "C" void kernel_launch(void* const* d_in, const int* in_sizes, int n_in,
                              void* d_out, int out_size, void* d_ws, size_t ws_size,
                              hipStream_t stream) {
  const float* inputs = (const float*)d_in[0];
  const int* seqlen = (const int*)d_in[1];
  const float* Wx_f = (const float*)d_in[2];
  const float* Wh_f = (const float*)d_in[3];
  const float* b_f  = (const float*)d_in[4];
  const float* Wx_b = (const float*)d_in[5];
  const float* Wh_b = (const float*)d_in[6];
  const float* b_b  = (const float*)d_in[7];
  const float* Wp   = (const float*)d_in[8];
  const float* bp   = (const float*)d_in[9];
  float* out = (float*)d_out;

  // ws: diag(256B) | hbuf u64 @256 (128KiB) | Pf | Pb | cat | x1 (fp16)
  const size_t oHB = 256;
  const size_t szHB = (size_t)2 * 16 * HH * sizeof(unsigned long long);  // 131072
  const size_t oPf = oHB + szHB;
  const size_t oPb = oPf + 67108864ull;
  const size_t oCat = oPb + 67108864ull;
  const size_t oX1 = oCat + 33554432ull;
  const size_t need = oX1 + 16777216ull;

  if (ws_size < need) {
    hipMemsetAsync(d_out, 0, (size_t)out_size * sizeof(float), stream);
    float code = 1.0e8f + (float)(ws_size / (1024.0 * 1024.0)) * 10.0f;
    diag_mark<<<1, 1, 0, stream>>>(nullptr, out, code, 1);
    return;
  }
  char* ws = (char*)d_ws;
  float* diag = (float*)ws;
  unsigned long long* hbuf = (unsigned long long*)(ws + oHB);
  __half* Pf = (__half*)(ws + oPf);
  __half* Pb = (__half*)(ws + oPb);
  __half* cat = (__half*)(ws + oCat);
  __half* x1 = (__half*)(ws + oX1);

  hipMemsetAsync(diag, 0, 256, stream);

  const int MM = NB * T_LEN;  // 16384

  // ---- layer 0 (A = fp32 inputs) ----
  gemm_bias<float, __half><<<dim3((MM / 128) * (G4 / 128)), dim3(256), 0, stream>>>(
      inputs, Wx_f, b_f, Pf, MM, G4, DD);
  gemm_bias<float, __half><<<dim3((MM / 128) * (G4 / 128)), dim3(256), 0, stream>>>(
      inputs, Wx_b, b_b, Pb, MM, G4, DD);
  lstm_scan<<<dim3(128), dim3(512), 0, stream>>>(Pf, Pb, Wh_f, Wh_b, seqlen, cat,
                                                 hbuf, diag, 1);
  gemm_bias<__half, __half><<<dim3((MM / 128) * (DD / 128)), dim3(256), 0, stream>>>(
      cat, Wp, bp, x1, MM, DD, CAT2H);

  // ---- layer 1 (A = fp16 x1) ----
  gemm_bias<__half, __half><<<dim3((MM / 128) * (G4 / 128)), dim3(256), 0, stream>>>(
      x1, Wx_f + (size_t)DD * G4, b_f + G4, Pf, MM, G4, DD);
  gemm_bias<__half, __half><<<dim3((MM / 128) * (G4 / 128)), dim3(256), 0, stream>>>(
      x1, Wx_b + (size_t)DD * G4, b_b + G4, Pb, MM, G4, DD);
  lstm_scan<<<dim3(128), dim3(512), 0, stream>>>(
      Pf, Pb, Wh_f + (size_t)HH * G4, Wh_b + (size_t)HH * G4, seqlen, cat, hbuf,
      diag, 3000);
  gemm_bias<__half, float><<<dim3((MM / 128) * (DD / 128)), dim3(256), 0, stream>>>(
      cat, Wp + (size_t)CAT2H * DD, bp + DD, out, MM, DD, CAT2H);

  diag_mark<<<1, 1, 0, stream>>>(diag, out, 0.f, 0);
}

// Round 11
// 8273.121 us; speedup vs baseline: 4.8355x; 4.8355x over previous
//
#include <hip/hip_runtime.h>
#include <hip/hip_fp16.h>
#include <math.h>

#define T_LEN 2048
#define NB 8
#define DD 512
#define HH 512
#define G4 2048   // 4*H
#define CAT2H 1024

typedef _Float16 h2_t __attribute__((ext_vector_type(2)));

__device__ __forceinline__ h2_t f2h2(float x, float y) {
  h2_t r; r[0] = (_Float16)x; r[1] = (_Float16)y; return r;
}

// ---------- vector load helpers (fp32 or fp16 -> float4) ----------
__device__ __forceinline__ float4 ld4(const float* p) { return *(const float4*)p; }
__device__ __forceinline__ float4 ld4(const __half* p) {
  const __half2 a = *(const __half2*)p;
  const __half2 b = *(const __half2*)(p + 2);
  return make_float4(__half2float(a.x), __half2float(a.y),
                     __half2float(b.x), __half2float(b.y));
}
__device__ __forceinline__ void st4(float* p, float4 v) { *(float4*)p = v; }
__device__ __forceinline__ void st4(__half* p, float4 v) {
  *(__half2*)p = __floats2half2_rn(v.x, v.y);
  *(__half2*)(p + 2) = __floats2half2_rn(v.z, v.w);
}

// -------- tiled GEMM + bias, fdot2 inner loop (fp16 staged, fp32 accum) --------
// C = A(MxK) @ B(KxN) + bias. blockIdx.y selects (B0,bias0,C0)/(B1,bias1,C1)
// so the two per-layer input-projection GEMMs run in ONE dispatch.
template <typename TA, typename TC>
__global__ __launch_bounds__(256) void gemm_bias(
    const TA* __restrict__ A, const float* __restrict__ B0,
    const float* __restrict__ B1, const float* __restrict__ bias0,
    const float* __restrict__ bias1, TC* __restrict__ C0, TC* __restrict__ C1,
    int M, int N, int K) {
  const float* __restrict__ B = blockIdx.y ? B1 : B0;
  const float* __restrict__ bias = blockIdx.y ? bias1 : bias0;
  TC* __restrict__ C = blockIdx.y ? C1 : C0;
  __shared__ h2_t As2[8][132];  // [k-pair][m], +4 pad: conflict-free staging
  __shared__ h2_t Bs2[8][132];  // [k-pair][n]
  const int nTiles = N >> 7;
  const int bx = blockIdx.x % nTiles;
  const int by = blockIdx.x / nTiles;
  const int tid = threadIdx.x;
  const int tx = tid & 15, ty = tid >> 4;
  const TA* Ab = A + (size_t)by * 128 * K;
  const float* Bb = B + ((size_t)bx << 7);
  float acc[8][8];
#pragma unroll
  for (int i = 0; i < 8; i++)
#pragma unroll
    for (int j = 0; j < 8; j++) acc[i][j] = 0.f;

  for (int k0 = 0; k0 < K; k0 += 16) {
    __syncthreads();
#pragma unroll
    for (int i = 0; i < 2; i++) {  // stage A: 128 m x 16 k -> k-pair packed
      int idx = i * 256 + tid;
      int m = idx >> 2, kv = idx & 3;
      float4 va = ld4(Ab + (size_t)m * K + k0 + kv * 4);
      As2[kv * 2][m] = f2h2(va.x, va.y);
      As2[kv * 2 + 1][m] = f2h2(va.z, va.w);
    }
#pragma unroll
    for (int i = 0; i < 2; i++) {  // stage B: 16 k x 128 n -> k-pair packed
      int idx = i * 256 + tid;
      int kp = idx >> 6, n0 = (idx & 63) * 2;
      const float* bp0 = Bb + (size_t)(k0 + 2 * kp) * N + n0;
      float2 r0 = *(const float2*)bp0;
      float2 r1 = *(const float2*)(bp0 + N);
      Bs2[kp][n0] = f2h2(r0.x, r1.x);
      Bs2[kp][n0 + 1] = f2h2(r0.y, r1.y);
    }
    __syncthreads();
#pragma unroll
    for (int kp = 0; kp < 8; kp++) {
      h2_t a2[8], b2[8];
      *(float4*)&a2[0] = *(const float4*)&As2[kp][ty * 8];
      *(float4*)&a2[4] = *(const float4*)&As2[kp][ty * 8 + 4];
      *(float4*)&b2[0] = *(const float4*)&Bs2[kp][tx * 8];
      *(float4*)&b2[4] = *(const float4*)&Bs2[kp][tx * 8 + 4];
#pragma unroll
      for (int i = 0; i < 8; i++)
#pragma unroll
        for (int j = 0; j < 8; j++)
          acc[i][j] = __builtin_amdgcn_fdot2(a2[i], b2[j], acc[i][j], false);
    }
  }
  const int row0 = by * 128 + ty * 8;
  const int col0 = bx * 128 + tx * 8;
  float bv[8];
  *(float4*)&bv[0] = *(const float4*)&bias[col0];
  *(float4*)&bv[4] = *(const float4*)&bias[col0 + 4];
#pragma unroll
  for (int i = 0; i < 8; i++) {
    float4 o0 = make_float4(acc[i][0] + bv[0], acc[i][1] + bv[1],
                            acc[i][2] + bv[2], acc[i][3] + bv[3]);
    float4 o1 = make_float4(acc[i][4] + bv[4], acc[i][5] + bv[5],
                            acc[i][6] + bv[6], acc[i][7] + bv[7]);
    st4(&C[(size_t)(row0 + i) * N + col0], o0);
    st4(&C[(size_t)(row0 + i) * N + col0 + 4], o1);
  }
}

// ---------------- persistent bidirectional LSTM scan (one layer) ----------------
// R5 geometry + protocol VERBATIM (twice-proven): 256 WGs x 512 thr; chain=
// (dir,b) -> 16 WGs; WG owns 32 units; u64 (tag|f32 h) relaxed AGENT atomics
// via LLC, double-buffered by step parity, tags unique per launch (1/3000).
// R11 delta (compute slice only, protocol untouched): Wh held as fp16 pairs
// (64 h2_t VGPRs), h mirrored into fp16 LDS, inner loop = 16 ds_read_b128 +
// 64 v_dot2_f32_f16 (fp32 accumulate; exact given fp16 inputs).
__device__ __forceinline__ float sigmf_(float x) {
  return 1.f / (1.f + __expf(-x));
}
__device__ __forceinline__ float tanhf_(float x) {
  return 1.f - 2.f / (1.f + __expf(2.f * x));
}

__global__ __launch_bounds__(512, 2) void lstm_scan(
    const __half* __restrict__ Pf, const __half* __restrict__ Pb,
    const float* __restrict__ Whf, const float* __restrict__ Whb,
    const int* __restrict__ seqlen, __half* __restrict__ cat,
    unsigned long long* hbuf, float* diag, int tagbase) {
  const int w = blockIdx.x;
  const int chain = w & 15;
  const int us = w >> 4;
  const int dir = chain & 1;
  const int b = chain >> 1;
  const int t = threadIdx.x;
  const int col = t & 127;
  const int kc = t >> 7;
  const int C = (col >> 5) * HH + us * 32 + (col & 31);

  const float* __restrict__ Wh = dir ? Whb : Whf;
  const __half* __restrict__ P = dir ? Pb : Pf;
  const int L = seqlen[b];

  __shared__ __half h16[HH];
  __shared__ float partial[4][128];

  h2_t wr2[64];
  {
    const float* wp = Wh + (size_t)(kc * 128) * G4 + C;
#pragma unroll
    for (int j = 0; j < 64; j++)
      wr2[j] = f2h2(wp[(size_t)(2 * j) * G4], wp[(size_t)(2 * j + 1) * G4]);
  }
  float c_state = 0.f;

  // hbuf: [slot(2)][dir(2)][b(8)][H] u64 (tag<<32 | f32 h bits)
  unsigned long long* hb_base = hbuf + ((size_t)dir * NB + b) * HH;
  const size_t slotStride = (size_t)2 * NB * HH;
  const unsigned tb = (unsigned)tagbase;

  if (t < 32) {  // init slot 0: h(-1)=0 tagged tb
    __hip_atomic_store(hb_base + us * 32 + t, ((unsigned long long)tb << 32),
                       __ATOMIC_RELAXED, __HIP_MEMORY_SCOPE_AGENT);
  }

  for (int s = 0; s < T_LEN; s++) {
    const int tin = dir ? ((s < L) ? (L - 1 - s) : s) : s;
    float p0 = 0.f, p1 = 0.f, p2 = 0.f, p3 = 0.f;
    if (t < 32) {  // P prefetch; latency hides under the spin
      const __half* pr = P + ((size_t)b * T_LEN + tin) * G4 + us * 32 + t;
      p0 = __half2float(pr[0]);
      p1 = __half2float(pr[HH]);
      p2 = __half2float(pr[2 * HH]);
      p3 = __half2float(pr[3 * HH]);
    }

    // spin: unit t must carry tag == tb+s (R5 protocol, unchanged)
    int dead = 0;
    {
      const unsigned want = tb + (unsigned)s;
      unsigned long long* hp = hb_base + (size_t)(s & 1) * slotStride + t;
      unsigned long long v;
      int tries = 0;
      for (;;) {
        v = __hip_atomic_load(hp, __ATOMIC_RELAXED, __HIP_MEMORY_SCOPE_AGENT);
        if ((unsigned)(v >> 32) == want) break;
        if (++tries > (1 << 20)) { dead = 1; break; }
      }
      h16[t] = __float2half(__uint_as_float((unsigned)v));
    }
    if (__syncthreads_or(dead)) {  // barrier B: h16 ready (or clean abort)
      if (t == 0) { atomicAdd(diag + 1, 1.0f); diag[2] = (float)s; }
      break;
    }

    float a0 = 0.f, a1 = 0.f, a2 = 0.f, a3 = 0.f;
    const __half* hk = &h16[kc * 128];
#pragma unroll
    for (int jj = 0; jj < 16; jj++) {
      float4 hv4 = *(const float4*)&hk[jj * 8];  // 8 halfs; uniform addr: bcast
      const h2_t* hp2 = (const h2_t*)&hv4;
      a0 = __builtin_amdgcn_fdot2(hp2[0], wr2[jj * 4 + 0], a0, false);
      a1 = __builtin_amdgcn_fdot2(hp2[1], wr2[jj * 4 + 1], a1, false);
      a2 = __builtin_amdgcn_fdot2(hp2[2], wr2[jj * 4 + 2], a2, false);
      a3 = __builtin_amdgcn_fdot2(hp2[3], wr2[jj * 4 + 3], a3, false);
    }
    partial[kc][col] = (a0 + a1) + (a2 + a3);
    __syncthreads();  // barrier C

    if (t < 32) {
      float g0 = p0, g1 = p1, g2 = p2, g3 = p3;
#pragma unroll
      for (int k2 = 0; k2 < 4; k2++) {
        g0 += partial[k2][t];
        g1 += partial[k2][32 + t];
        g2 += partial[k2][64 + t];
        g3 += partial[k2][96 + t];
      }
      c_state = sigmf_(g1) * c_state + sigmf_(g0) * tanhf_(g2);
      float hn = sigmf_(g3) * tanhf_(c_state);
      unsigned long long pv =
          ((unsigned long long)(tb + (unsigned)s + 1u) << 32) |
          (unsigned long long)__float_as_uint(hn);
      __hip_atomic_store(hb_base + (size_t)((s + 1) & 1) * slotStride + us * 32 + t,
                         pv, __ATOMIC_RELAXED, __HIP_MEMORY_SCOPE_AGENT);
      cat[((size_t)b * T_LEN + tin) * CAT2H + dir * HH + us * 32 + t] =
          __float2half(hn);
    }
    // no trailing barrier: h16/partial reuse gated by barriers B/C (R5 proof).
  }
}

// Failure-signature marker: writes a decodable code into out[0] ONLY on failure.
__global__ void diag_mark(const float* diag, float* out, float code_ws, int wsfail) {
  if (wsfail) { out[0] = code_ws; return; }
  float nd = diag[1];
  if (nd > 0.f) out[0] = 1.0e7f + nd * 1.0e4f + diag[2];
}

extern "C" void kernel_launch(void* const* d_in, const int* in_sizes, int n_in,
                              void* d_out, int out_size, void* d_ws, size_t ws_size,
                              hipStream_t stream) {
  const float* inputs = (const float*)d_in[0];
  const int* seqlen = (const int*)d_in[1];
  const float* Wx_f = (const float*)d_in[2];
  const float* Wh_f = (const float*)d_in[3];
  const float* b_f  = (const float*)d_in[4];
  const float* Wx_b = (const float*)d_in[5];
  const float* Wh_b = (const float*)d_in[6];
  const float* b_b  = (const float*)d_in[7];
  const float* Wp   = (const float*)d_in[8];
  const float* bp   = (const float*)d_in[9];
  float* out = (float*)d_out;

  // ws: diag(256B) | hbuf u64 @256 (128KiB) | Pf | Pb | cat | x1 (fp16)
  const size_t oHB = 256;
  const size_t szHB = (size_t)2 * 16 * HH * sizeof(unsigned long long);  // 131072
  const size_t oPf = oHB + szHB;
  const size_t oPb = oPf + 67108864ull;
  const size_t oCat = oPb + 67108864ull;
  const size_t oX1 = oCat + 33554432ull;
  const size_t need = oX1 + 16777216ull;

  if (ws_size < need) {
    hipMemsetAsync(d_out, 0, (size_t)out_size * sizeof(float), stream);
    float code = 1.0e8f + (float)(ws_size / (1024.0 * 1024.0)) * 10.0f;
    diag_mark<<<1, 1, 0, stream>>>(nullptr, out, code, 1);
    return;
  }
  char* ws = (char*)d_ws;
  float* diag = (float*)ws;
  unsigned long long* hbuf = (unsigned long long*)(ws + oHB);
  __half* Pf = (__half*)(ws + oPf);
  __half* Pb = (__half*)(ws + oPb);
  __half* cat = (__half*)(ws + oCat);
  __half* x1 = (__half*)(ws + oX1);

  hipMemsetAsync(diag, 0, 256, stream);

  const int MM = NB * T_LEN;  // 16384

  // ---- layer 0: both input projections in ONE dispatch (blockIdx.y) ----
  gemm_bias<float, __half>
      <<<dim3((MM / 128) * (G4 / 128), 2), dim3(256), 0, stream>>>(
          inputs, Wx_f, Wx_b, b_f, b_b, Pf, Pb, MM, G4, DD);
  lstm_scan<<<dim3(256), dim3(512), 0, stream>>>(Pf, Pb, Wh_f, Wh_b, seqlen, cat,
                                                 hbuf, diag, 1);
  gemm_bias<__half, __half>
      <<<dim3((MM / 128) * (DD / 128), 1), dim3(256), 0, stream>>>(
          cat, Wp, Wp, bp, bp, x1, x1, MM, DD, CAT2H);

  // ---- layer 1 ----
  gemm_bias<__half, __half>
      <<<dim3((MM / 128) * (G4 / 128), 2), dim3(256), 0, stream>>>(
          x1, Wx_f + (size_t)DD * G4, Wx_b + (size_t)DD * G4, b_f + G4, b_b + G4,
          Pf, Pb, MM, G4, DD);
  lstm_scan<<<dim3(256), dim3(512), 0, stream>>>(
      Pf, Pb, Wh_f + (size_t)HH * G4, Wh_b + (size_t)HH * G4, seqlen, cat, hbuf,
      diag, 3000);
  gemm_bias<__half, float>
      <<<dim3((MM / 128) * (DD / 128), 1), dim3(256), 0, stream>>>(
          cat, Wp + (size_t)CAT2H * DD, Wp + (size_t)CAT2H * DD, bp + DD,
          bp + DD, out, out, MM, DD, CAT2H);

  diag_mark<<<1, 1, 0, stream>>>(diag, out, 0.f, 0);
}